// Round 1
// baseline (734.205 us; speedup 1.0000x reference)
//
#include <hip/hip_runtime.h>
#include <hip/hip_bf16.h>
#include <stdint.h>

// Problem constants (fixed by the reference)
#define N_NODES 50000
#define E_EDGES 640000
#define NB_TILES 782           // ceil(50000/64)

typedef __attribute__((ext_vector_type(8))) short short8;   // 8 bf16 = 4 VGPRs (MFMA A/B frag)
typedef __attribute__((ext_vector_type(4))) float float4v;  // MFMA C/D frag

__device__ __forceinline__ unsigned short f32_to_bf16(float f) {
  uint32_t u = __float_as_uint(f);
  u += 0x7fffu + ((u >> 16) & 1u);          // round-to-nearest-even
  return (unsigned short)(u >> 16);
}

// ---------------------------------------------------------------------------
// K0: transpose + convert the 11 [128][128] f32 weight matrices into a bf16
// bank wTg[m][o][k] (k-fast) so later LDS staging is fully coalesced and
// conflict-free. m: 0..7 = W_rel[r], 8 = w1_W, 9 = m1_W, 10 = m2_W.
// ---------------------------------------------------------------------------
__global__ __launch_bounds__(256) void k0_tw(
    const float* __restrict__ W_rel, const float* __restrict__ w1W,
    const float* __restrict__ m1W, const float* __restrict__ m2W,
    unsigned short* __restrict__ wTg) {
  int m = blockIdx.x;
  const float* srcp = (m < 8) ? (W_rel + (size_t)m * 16384)
                              : (m == 8 ? w1W : (m == 9 ? m1W : m2W));
  unsigned short* dstp = wTg + (size_t)m * 16384;
  int tid = threadIdx.x;
  for (int i = 0; i < 64; ++i) {
    int idx = tid + i * 256;          // output flat index o*128 + k
    int o = idx >> 7, k = idx & 127;
    dstp[idx] = f32_to_bf16(srcp[k * 128 + o]);   // strided read, tiny & L2-cached
  }
}

// ---------------------------------------------------------------------------
// Shared device helpers for the MFMA tile kernels.
// LDS rows are padded to 136 shorts (272 B, 16B-aligned) to break bank-conflict
// power-of-2 strides while keeping ds_read_b128 alignment.
// ---------------------------------------------------------------------------
__device__ __forceinline__ void load_x_tile(const float* __restrict__ x,
                                            short (*xs)[136], int tile0, int tid) {
  for (int i = 0; i < 16; ++i) {
    int idx = tid + i * 256;          // 4096 float2 over 64x128
    int row = idx >> 6, c2 = idx & 63;
    int node = tile0 + row;
    float2 v = make_float2(0.f, 0.f);
    if (node < N_NODES) v = *(const float2*)&x[(size_t)node * 128 + c2 * 2];
    uint32_t p = (uint32_t)f32_to_bf16(v.x) | ((uint32_t)f32_to_bf16(v.y) << 16);
    *(uint32_t*)&xs[row][c2 * 2] = p;
  }
}

__device__ __forceinline__ void load_w_tile(const unsigned short* __restrict__ wsrc,
                                            short (*wT)[136], int tid) {
  const uint32_t* s = (const uint32_t*)wsrc;   // already bf16 [o][k], k-fast
  #pragma unroll
  for (int i = 0; i < 32; ++i) {
    int idx = tid + i * 256;          // 8192 u32
    int n = idx >> 6, kw = idx & 63;
    *(uint32_t*)&wT[n][kw * 2] = s[idx];
  }
}

// One wave computes a 16x128 output tile: rows wave*16..+15, all 128 cols.
// A frag: A[row=lane&15][k=(lane>>4)*8 + j]; B frag: B[k][col=lane&15] read
// from the transposed LDS copy; D: col=lane&15, row=(lane>>4)*4+i (verified
// layout, learn_hip m89/m91).
__device__ __forceinline__ void gemm_tile(const short (*A)[136], const short (*Bt)[136],
                                          int wave, int lane, float4v acc[8]) {
  int arow = wave * 16 + (lane & 15);
  int koff = (lane >> 4) * 8;
  #pragma unroll
  for (int kk = 0; kk < 4; ++kk) {
    short8 a = *(const short8*)&A[arow][kk * 32 + koff];
    #pragma unroll
    for (int n = 0; n < 8; ++n) {
      short8 b = *(const short8*)&Bt[n * 16 + (lane & 15)][kk * 32 + koff];
      acc[n] = __builtin_amdgcn_mfma_f32_16x16x32_bf16(a, b, acc[n], 0, 0, 0);
    }
  }
}

// ---------------------------------------------------------------------------
// K1: h_all[n][r][o] (bf16) = x[n][:] @ W_rel[r].  64-node tile per block,
// 4 waves, loop r with W_r staged from the L2-resident transposed bank.
// ---------------------------------------------------------------------------
__global__ __launch_bounds__(256) void k1_hall(
    const float* __restrict__ x, const unsigned short* __restrict__ wTg,
    unsigned short* __restrict__ h_all) {
  __shared__ short xs[64][136];
  __shared__ short wT[128][136];
  __shared__ short hs[4][16][136];   // per-wave write-staging for coalesced stores
  int tid = threadIdx.x, wave = tid >> 6, lane = tid & 63;
  int tile0 = blockIdx.x * 64;

  load_x_tile(x, xs, tile0, tid);

  for (int r = 0; r < 8; ++r) {
    __syncthreads();                         // prev iter's wT reads done
    load_w_tile(wTg + (size_t)r * 16384, wT, tid);
    __syncthreads();

    float4v acc[8];
    #pragma unroll
    for (int n = 0; n < 8; ++n) acc[n] = (float4v){0.f, 0.f, 0.f, 0.f};
    gemm_tile(xs, wT, wave, lane, acc);

    // stage bf16 results (wave-private rows), then coalesced 256B row stores
    #pragma unroll
    for (int n = 0; n < 8; ++n)
      #pragma unroll
      for (int i = 0; i < 4; ++i)
        hs[wave][(lane >> 4) * 4 + i][n * 16 + (lane & 15)] = (short)f32_to_bf16(acc[n][i]);
    #pragma unroll
    for (int i = 0; i < 16; ++i) {
      int node = tile0 + wave * 16 + i;
      if (node < N_NODES)
        ((uint32_t*)h_all)[((size_t)node * 8 + r) * 64 + lane] =
            *(const uint32_t*)&hs[wave][i][lane * 2];
    }
  }
}

// ---------------------------------------------------------------------------
// K2: per-edge gather of h_all[src,etype] (256B coalesced row) + f32 atomic
// scatter-add into agg[dst].  One wave per edge, 2 elems per lane.
// ---------------------------------------------------------------------------
__global__ __launch_bounds__(256) void k2_scatter(
    const unsigned short* __restrict__ h_all, const int* __restrict__ src,
    const int* __restrict__ dst, const int* __restrict__ ety,
    float* __restrict__ agg) {
  int e = blockIdx.x * 4 + (threadIdx.x >> 6);
  int lane = threadIdx.x & 63;
  int s = src[e], t = dst[e], r = ety[e];
  uint32_t v = ((const uint32_t*)h_all)[((size_t)s * 8 + r) * 64 + lane];
  float f0 = __uint_as_float(v << 16);            // low bf16
  float f1 = __uint_as_float(v & 0xffff0000u);    // high bf16
  float* ap = agg + (size_t)t * 128 + lane * 2;
  atomicAdd(ap, f0);
  atomicAdd(ap + 1, f1);
}

// ---------------------------------------------------------------------------
// K3: fused node update: h1 = x@w1 + b1 + agg; h2 = relu(h1@m1 + b1m);
// out = h2@m2 + b2m.  Three chained MFMA GEMMs through LDS per 64-node tile.
// ---------------------------------------------------------------------------
__global__ __launch_bounds__(256) void k3_update(
    const float* __restrict__ x, const float* __restrict__ agg,
    const unsigned short* __restrict__ wTg,
    const float* __restrict__ w1b, const float* __restrict__ m1b,
    const float* __restrict__ m2b, float* __restrict__ out) {
  __shared__ short xs[64][136];
  __shared__ short hs[64][136];
  __shared__ short wT[128][136];
  int tid = threadIdx.x, wave = tid >> 6, lane = tid & 63;
  int tile0 = blockIdx.x * 64;

  load_x_tile(x, xs, tile0, tid);
  load_w_tile(wTg + (size_t)8 * 16384, wT, tid);   // w1^T
  __syncthreads();

  float4v acc[8];

  // GEMM1: x @ w1 (+ b1 + agg) -> hs (bf16)
  #pragma unroll
  for (int n = 0; n < 8; ++n) acc[n] = (float4v){0.f, 0.f, 0.f, 0.f};
  gemm_tile(xs, wT, wave, lane, acc);
  #pragma unroll
  for (int n = 0; n < 8; ++n)
    #pragma unroll
    for (int i = 0; i < 4; ++i) {
      int row = wave * 16 + (lane >> 4) * 4 + i;
      int col = n * 16 + (lane & 15);
      int node = tile0 + row;
      float a = (node < N_NODES) ? agg[(size_t)node * 128 + col] : 0.f;
      hs[row][col] = (short)f32_to_bf16(acc[n][i] + w1b[col] + a);
    }
  __syncthreads();                    // wT reads + hs writes complete

  // GEMM2: h1 @ m1, relu -> xs (bf16, reuse)
  load_w_tile(wTg + (size_t)9 * 16384, wT, tid);   // m1^T
  __syncthreads();
  #pragma unroll
  for (int n = 0; n < 8; ++n) acc[n] = (float4v){0.f, 0.f, 0.f, 0.f};
  gemm_tile(hs, wT, wave, lane, acc);
  #pragma unroll
  for (int n = 0; n < 8; ++n)
    #pragma unroll
    for (int i = 0; i < 4; ++i) {
      int row = wave * 16 + (lane >> 4) * 4 + i;
      int col = n * 16 + (lane & 15);
      float v = acc[n][i] + m1b[col];
      xs[row][col] = (short)f32_to_bf16(v > 0.f ? v : 0.f);
    }
  __syncthreads();

  // GEMM3: h2 @ m2 + b2 -> out (f32)
  load_w_tile(wTg + (size_t)10 * 16384, wT, tid);  // m2^T
  __syncthreads();
  #pragma unroll
  for (int n = 0; n < 8; ++n) acc[n] = (float4v){0.f, 0.f, 0.f, 0.f};
  gemm_tile(xs, wT, wave, lane, acc);
  #pragma unroll
  for (int n = 0; n < 8; ++n)
    #pragma unroll
    for (int i = 0; i < 4; ++i) {
      int row = wave * 16 + (lane >> 4) * 4 + i;
      int col = n * 16 + (lane & 15);
      int node = tile0 + row;
      if (node < N_NODES) out[(size_t)node * 128 + col] = acc[n][i] + m2b[col];
    }
}

// ---------------------------------------------------------------------------
extern "C" void kernel_launch(void* const* d_in, const int* in_sizes, int n_in,
                              void* d_out, int out_size, void* d_ws, size_t ws_size,
                              hipStream_t stream) {
  const float* x     = (const float*)d_in[0];
  const int*   src   = (const int*)d_in[1];
  const int*   dst   = (const int*)d_in[2];
  const int*   ety   = (const int*)d_in[3];
  const float* W_rel = (const float*)d_in[4];
  const float* w1W   = (const float*)d_in[5];
  const float* w1b   = (const float*)d_in[6];
  const float* m1W   = (const float*)d_in[7];
  const float* m1b   = (const float*)d_in[8];
  const float* m2W   = (const float*)d_in[9];
  const float* m2b   = (const float*)d_in[10];
  float* out = (float*)d_out;

  // Workspace layout (bytes):
  //   [0, 360448)            : wTg  — 11 transposed bf16 weight matrices
  //   [524288, +102400000)   : h_all bf16 [N][R][128]
  //   [102924288, +25600000) : agg  f32  [N][128]
  unsigned short* wTg   = (unsigned short*)d_ws;
  unsigned short* h_all = (unsigned short*)((char*)d_ws + 524288);
  float*          agg   = (float*)((char*)d_ws + 102924288);

  hipMemsetAsync(agg, 0, (size_t)N_NODES * 128 * sizeof(float), stream);
  k0_tw<<<11, 256, 0, stream>>>(W_rel, w1W, m1W, m2W, wTg);
  k1_hall<<<NB_TILES, 256, 0, stream>>>(x, wTg, h_all);
  k2_scatter<<<E_EDGES / 4, 256, 0, stream>>>(h_all, src, dst, ety, agg);
  k3_update<<<NB_TILES, 256, 0, stream>>>(x, agg, wTg, w1b, m1b, m2b, out);
}

// Round 2
// 342.787 us; speedup vs baseline: 2.1419x; 2.1419x over previous
//
#include <hip/hip_runtime.h>
#include <hip/hip_bf16.h>
#include <stdint.h>

// Problem constants (fixed by the reference)
#define N_NODES 50000
#define E_EDGES 640000
#define NB_TILES 782           // ceil(50000/64)
#define NKEY 400000            // N_NODES * R
#define NKEYP 400384           // 391 * 1024 (scan-padded)
#define SCAN_BLOCKS 391

typedef __attribute__((ext_vector_type(8))) short short8;   // 8 bf16 = 4 VGPRs (MFMA A/B frag)
typedef __attribute__((ext_vector_type(4))) float float4v;  // MFMA C/D frag

__device__ __forceinline__ unsigned short f32_to_bf16(float f) {
  uint32_t u = __float_as_uint(f);
  u += 0x7fffu + ((u >> 16) & 1u);          // round-to-nearest-even
  return (unsigned short)(u >> 16);
}

// ---------------------------------------------------------------------------
// K0: transpose + convert the 11 [128][128] f32 weight matrices into a bf16
// bank wTg[m][o][k] (k-fast). m: 0..7 = W_rel[r], 8 = w1_W, 9 = m1_W, 10 = m2_W.
// ---------------------------------------------------------------------------
__global__ __launch_bounds__(256) void k0_tw(
    const float* __restrict__ W_rel, const float* __restrict__ w1W,
    const float* __restrict__ m1W, const float* __restrict__ m2W,
    unsigned short* __restrict__ wTg) {
  int m = blockIdx.x;
  const float* srcp = (m < 8) ? (W_rel + (size_t)m * 16384)
                              : (m == 8 ? w1W : (m == 9 ? m1W : m2W));
  unsigned short* dstp = wTg + (size_t)m * 16384;
  int tid = threadIdx.x;
  for (int i = 0; i < 64; ++i) {
    int idx = tid + i * 256;          // output flat index o*128 + k
    int o = idx >> 7, k = idx & 127;
    dstp[idx] = f32_to_bf16(srcp[k * 128 + o]);
  }
}

// ---------------------------------------------------------------------------
// CSR build: histogram by key = dst*8 + etype, exclusive scan, fill.
// ---------------------------------------------------------------------------
__global__ __launch_bounds__(256) void k_hist(
    const int* __restrict__ dst, const int* __restrict__ ety, int* __restrict__ cnt) {
  int e = blockIdx.x * 256 + threadIdx.x;
  if (e < E_EDGES) atomicAdd(&cnt[dst[e] * 8 + ety[e]], 1);
}

__global__ __launch_bounds__(1024) void k_scanA(
    const int* __restrict__ cnt, int* __restrict__ off, int* __restrict__ btot) {
  __shared__ int s[1024];
  int t = threadIdx.x, g = blockIdx.x * 1024 + t;
  int v = cnt[g];
  s[t] = v; __syncthreads();
  for (int d = 1; d < 1024; d <<= 1) {
    int a = (t >= d) ? s[t - d] : 0;
    __syncthreads();
    s[t] += a;
    __syncthreads();
  }
  off[g] = s[t] - v;                       // exclusive within block
  if (t == 1023) btot[blockIdx.x] = s[t];  // block total
}

__global__ __launch_bounds__(512) void k_scanB(int* __restrict__ btot) {
  __shared__ int s[512];
  int t = threadIdx.x;
  int v = (t < SCAN_BLOCKS) ? btot[t] : 0;
  s[t] = v; __syncthreads();
  for (int d = 1; d < 512; d <<= 1) {
    int a = (t >= d) ? s[t - d] : 0;
    __syncthreads();
    s[t] += a;
    __syncthreads();
  }
  if (t < SCAN_BLOCKS) btot[t] = s[t] - v; // exclusive, in-place
}

__global__ __launch_bounds__(1024) void k_scanC(
    int* __restrict__ off, const int* __restrict__ btot) {
  int g = blockIdx.x * 1024 + threadIdx.x;
  off[g] += btot[blockIdx.x];
}

__global__ __launch_bounds__(256) void k_fill(
    const int* __restrict__ src, const int* __restrict__ dst,
    const int* __restrict__ ety, const int* __restrict__ off,
    int* __restrict__ cur, int* __restrict__ eidx) {
  int e = blockIdx.x * 256 + threadIdx.x;
  if (e >= E_EDGES) return;
  int key = dst[e] * 8 + ety[e];
  int p = off[key] + atomicAdd(&cur[key], 1);
  eidx[p] = src[e] * 8 + ety[e];           // = h_all row index of this message
}

// ---------------------------------------------------------------------------
// LDS helpers (rows padded to 136 shorts = 272B, 16B-aligned).
// ---------------------------------------------------------------------------
__device__ __forceinline__ void load_x_tile(const float* __restrict__ x,
                                            short (*xs)[136], int tile0, int tid) {
  for (int i = 0; i < 16; ++i) {
    int idx = tid + i * 256;          // 4096 float2 over 64x128
    int row = idx >> 6, c2 = idx & 63;
    int node = tile0 + row;
    float2 v = make_float2(0.f, 0.f);
    if (node < N_NODES) v = *(const float2*)&x[(size_t)node * 128 + c2 * 2];
    uint32_t p = (uint32_t)f32_to_bf16(v.x) | ((uint32_t)f32_to_bf16(v.y) << 16);
    *(uint32_t*)&xs[row][c2 * 2] = p;
  }
}

__device__ __forceinline__ void load_w_tile(const unsigned short* __restrict__ wsrc,
                                            short (*wT)[136], int tid) {
  const uint32_t* s = (const uint32_t*)wsrc;   // bf16 [o][k], k-fast
  #pragma unroll
  for (int i = 0; i < 32; ++i) {
    int idx = tid + i * 256;          // 8192 u32
    int n = idx >> 6, kw = idx & 63;
    *(uint32_t*)&wT[n][kw * 2] = s[idx];
  }
}

// One wave computes a 16x128 output tile (D layout: col=lane&15, row=(lane>>4)*4+i).
__device__ __forceinline__ void gemm_tile(const short (*A)[136], const short (*Bt)[136],
                                          int wave, int lane, float4v acc[8]) {
  int arow = wave * 16 + (lane & 15);
  int koff = (lane >> 4) * 8;
  #pragma unroll
  for (int kk = 0; kk < 4; ++kk) {
    short8 a = *(const short8*)&A[arow][kk * 32 + koff];
    #pragma unroll
    for (int n = 0; n < 8; ++n) {
      short8 b = *(const short8*)&Bt[n * 16 + (lane & 15)][kk * 32 + koff];
      acc[n] = __builtin_amdgcn_mfma_f32_16x16x32_bf16(a, b, acc[n], 0, 0, 0);
    }
  }
}

// ---------------------------------------------------------------------------
// K1: h_all[n][r][o] (bf16) = x[n][:] @ W_rel[r].
// ---------------------------------------------------------------------------
__global__ __launch_bounds__(256) void k1_hall(
    const float* __restrict__ x, const unsigned short* __restrict__ wTg,
    unsigned short* __restrict__ h_all) {
  __shared__ short xs[64][136];
  __shared__ short wT[128][136];
  __shared__ short hs[4][16][136];
  int tid = threadIdx.x, wave = tid >> 6, lane = tid & 63;
  int tile0 = blockIdx.x * 64;

  load_x_tile(x, xs, tile0, tid);

  for (int r = 0; r < 8; ++r) {
    __syncthreads();
    load_w_tile(wTg + (size_t)r * 16384, wT, tid);
    __syncthreads();

    float4v acc[8];
    #pragma unroll
    for (int n = 0; n < 8; ++n) acc[n] = (float4v){0.f, 0.f, 0.f, 0.f};
    gemm_tile(xs, wT, wave, lane, acc);

    #pragma unroll
    for (int n = 0; n < 8; ++n)
      #pragma unroll
      for (int i = 0; i < 4; ++i)
        hs[wave][(lane >> 4) * 4 + i][n * 16 + (lane & 15)] = (short)f32_to_bf16(acc[n][i]);
    #pragma unroll
    for (int i = 0; i < 16; ++i) {
      int node = tile0 + wave * 16 + i;
      if (node < N_NODES)
        ((uint32_t*)h_all)[((size_t)node * 8 + r) * 64 + lane] =
            *(const uint32_t*)&hs[wave][i][lane * 2];
    }
  }
}

// ---------------------------------------------------------------------------
// K_agg: one wave per destination node; gather h_all rows per CSR span,
// accumulate in f32 registers, one coalesced store. No atomics.
// ---------------------------------------------------------------------------
__global__ __launch_bounds__(256) void k_agg(
    const unsigned short* __restrict__ h_all, const int* __restrict__ eidx,
    const int* __restrict__ off, float* __restrict__ agg) {
  int v = blockIdx.x * 4 + (threadIdx.x >> 6);
  if (v >= N_NODES) return;
  int lane = threadIdx.x & 63;
  int s0 = off[v * 8], s1 = off[v * 8 + 8];   // full span across the 8 rels
  float a0 = 0.f, a1 = 0.f;
  for (int i = s0; i < s1; ++i) {
    uint32_t key = (uint32_t)eidx[i];         // src*8 + r
    uint32_t w = ((const uint32_t*)h_all)[(size_t)key * 64 + lane];
    a0 += __uint_as_float(w << 16);           // col 2*lane
    a1 += __uint_as_float(w & 0xffff0000u);   // col 2*lane+1
  }
  *(float2*)&agg[(size_t)v * 128 + lane * 2] = make_float2(a0, a1);
}

// ---------------------------------------------------------------------------
// K3: fused node update: h1 = x@w1 + b1 + agg; h2 = relu(h1@m1 + b1m);
// out = h2@m2 + b2m.
// ---------------------------------------------------------------------------
__global__ __launch_bounds__(256) void k3_update(
    const float* __restrict__ x, const float* __restrict__ agg,
    const unsigned short* __restrict__ wTg,
    const float* __restrict__ w1b, const float* __restrict__ m1b,
    const float* __restrict__ m2b, float* __restrict__ out) {
  __shared__ short xs[64][136];
  __shared__ short hs[64][136];
  __shared__ short wT[128][136];
  int tid = threadIdx.x, wave = tid >> 6, lane = tid & 63;
  int tile0 = blockIdx.x * 64;

  load_x_tile(x, xs, tile0, tid);
  load_w_tile(wTg + (size_t)8 * 16384, wT, tid);   // w1^T
  __syncthreads();

  float4v acc[8];

  // GEMM1: x @ w1 (+ b1 + agg) -> hs (bf16)
  #pragma unroll
  for (int n = 0; n < 8; ++n) acc[n] = (float4v){0.f, 0.f, 0.f, 0.f};
  gemm_tile(xs, wT, wave, lane, acc);
  #pragma unroll
  for (int n = 0; n < 8; ++n)
    #pragma unroll
    for (int i = 0; i < 4; ++i) {
      int row = wave * 16 + (lane >> 4) * 4 + i;
      int col = n * 16 + (lane & 15);
      int node = tile0 + row;
      float a = (node < N_NODES) ? agg[(size_t)node * 128 + col] : 0.f;
      hs[row][col] = (short)f32_to_bf16(acc[n][i] + w1b[col] + a);
    }
  __syncthreads();

  // GEMM2: h1 @ m1, relu -> xs (reuse)
  load_w_tile(wTg + (size_t)9 * 16384, wT, tid);   // m1^T
  __syncthreads();
  #pragma unroll
  for (int n = 0; n < 8; ++n) acc[n] = (float4v){0.f, 0.f, 0.f, 0.f};
  gemm_tile(hs, wT, wave, lane, acc);
  #pragma unroll
  for (int n = 0; n < 8; ++n)
    #pragma unroll
    for (int i = 0; i < 4; ++i) {
      int row = wave * 16 + (lane >> 4) * 4 + i;
      int col = n * 16 + (lane & 15);
      float v = acc[n][i] + m1b[col];
      xs[row][col] = (short)f32_to_bf16(v > 0.f ? v : 0.f);
    }
  __syncthreads();

  // GEMM3: h2 @ m2 + b2 -> out (f32)
  load_w_tile(wTg + (size_t)10 * 16384, wT, tid);  // m2^T
  __syncthreads();
  #pragma unroll
  for (int n = 0; n < 8; ++n) acc[n] = (float4v){0.f, 0.f, 0.f, 0.f};
  gemm_tile(xs, wT, wave, lane, acc);
  #pragma unroll
  for (int n = 0; n < 8; ++n)
    #pragma unroll
    for (int i = 0; i < 4; ++i) {
      int row = wave * 16 + (lane >> 4) * 4 + i;
      int col = n * 16 + (lane & 15);
      int node = tile0 + row;
      if (node < N_NODES) out[(size_t)node * 128 + col] = acc[n][i] + m2b[col];
    }
}

// ---------------------------------------------------------------------------
extern "C" void kernel_launch(void* const* d_in, const int* in_sizes, int n_in,
                              void* d_out, int out_size, void* d_ws, size_t ws_size,
                              hipStream_t stream) {
  const float* x     = (const float*)d_in[0];
  const int*   src   = (const int*)d_in[1];
  const int*   dst   = (const int*)d_in[2];
  const int*   ety   = (const int*)d_in[3];
  const float* W_rel = (const float*)d_in[4];
  const float* w1b   = (const float*)d_in[6];
  const float* m1b   = (const float*)d_in[8];
  const float* m2b   = (const float*)d_in[10];
  const float* w1W   = (const float*)d_in[5];
  const float* m1W   = (const float*)d_in[7];
  const float* m2W   = (const float*)d_in[9];
  float* out = (float*)d_out;

  // Workspace layout (bytes):
  char* ws = (char*)d_ws;
  unsigned short* wTg   = (unsigned short*)ws;                  // [0, 524288)
  unsigned short* h_all = (unsigned short*)(ws + 524288);       // 102,400,000
  float*          agg   = (float*)(ws + 102924288);             // 25,600,000
  int*            cnt   = (int*)(ws + 128524288);               // NKEYP*4 = 1,601,536
  int*            off   = (int*)(ws + 130125824);               // NKEYP*4
  int*            btot  = (int*)(ws + 131727360);               // 4 KB reserve
  int*            cur   = (int*)(ws + 131731456);               // NKEY*4 = 1,600,000
  int*            eidx  = (int*)(ws + 133331456);               // E*4 = 2,560,000

  hipMemsetAsync(cnt, 0, (size_t)NKEYP * 4, stream);
  hipMemsetAsync(cur, 0, (size_t)NKEY * 4, stream);

  k0_tw<<<11, 256, 0, stream>>>(W_rel, w1W, m1W, m2W, wTg);
  k_hist<<<E_EDGES / 256, 256, 0, stream>>>(dst, ety, cnt);
  k_scanA<<<SCAN_BLOCKS, 1024, 0, stream>>>(cnt, off, btot);
  k_scanB<<<1, 512, 0, stream>>>(btot);
  k_scanC<<<SCAN_BLOCKS, 1024, 0, stream>>>(off, btot);
  k_fill<<<E_EDGES / 256, 256, 0, stream>>>(src, dst, ety, off, cur, eidx);
  k1_hall<<<NB_TILES, 256, 0, stream>>>(x, wTg, h_all);
  k_agg<<<(N_NODES + 3) / 4, 256, 0, stream>>>(h_all, eidx, off, agg);
  k3_update<<<NB_TILES, 256, 0, stream>>>(x, agg, wTg, w1b, m1b, m2b, out);
}